// Round 21
// baseline (40.839 us; speedup 1.0000x reference)
//
#include <hip/hip_runtime.h>

// CTC batch cost (Keras: blank=C-1, full lengths).
// Structure (proven absmax 0.0 since R17): fwd/bwd split, 128 blocks;
//   block 2b+0 = forward alpha t=0..511, 2b+1 = backward beta t=1023..512;
//   P(y)=sum_s alpha*beta via ctc_combine. Consumer = R17 8-deep LDS ring +
//   DPP chain + per-lane pow2 rescale.
// R20 analysis: per-CU streaming rate ~30 GB/s (12.5 B/cyc) is the invariant
//   pacer across R16 (64 CUs) and R17-R20 (128 CUs); producer streams
//   2KB/step at that rate = ~164 cyc/step = measured. Consumer hides under.
// R21 experiment: TWO streaming waves per block (each stages half of each
//   chunk) to test whether the ~30 GB/s/CU is a per-wave limit (outstanding
//   capacity) or a per-CU fabric share. If per-wave: ~2x. If fabric: null
//   -> structural roofline (sequential DP caps useful CUs at B*2=128).

constexpr int   B_DIM = 64;
constexpr int   T_LEN = 1024;
constexpr int   C_DIM = 512;
constexpr int   L_LEN = 128;
constexpr int   BLANK = C_DIM - 1;
constexpr int   HALF  = T_LEN / 2;     // 512 steps per direction
constexpr int   TC    = 32;            // timesteps per chunk
constexpr int   NCH   = HALF / TC;     // 16 chunks
constexpr int   TH    = TC / 2;        // rows per producer wave
constexpr float EPSF  = 1e-7f;
constexpr float LN2F  = 0.69314718055994530942f;

// DPP lane shifts (bound_ctrl=0-fill). 0x138: lane l <- l-1 (verified R2-R20).
__device__ __forceinline__ float wshr1_f(float x) {
    return __int_as_float(__builtin_amdgcn_update_dpp(
        0, __float_as_int(x), 0x138, 0xf, 0xf, true));
}
__device__ __forceinline__ int wshr1_i(int x) {
    return __builtin_amdgcn_update_dpp(0, x, 0x138, 0xf, 0xf, true);
}
// 0x130: lane l <- l+1 (wave_shl:1), lane 63 gets 0. (verified R17)
__device__ __forceinline__ float wshl1_f(float x) {
    return __int_as_float(__builtin_amdgcn_update_dpp(
        0, __float_as_int(x), 0x130, 0xf, 0xf, true));
}
__device__ __forceinline__ int wshl1_i(int x) {
    return __builtin_amdgcn_update_dpp(0, x, 0x130, 0xf, 0xf, true);
}

__global__ __launch_bounds__(192, 1)
void ctc_fb(const int* __restrict__ yt, const float* __restrict__ yh,
            float* __restrict__ st)
{
    __shared__ float sbuf[2][TC][C_DIM];      // 128 KB

    const int bid  = blockIdx.x;
    const int b    = bid >> 1;
    const int dir  = bid & 1;                 // 0 = forward, 1 = backward
    const int tid  = threadIdx.x;
    const int lane = tid & 63;
    const int wid  = tid >> 6;                // 0 consumer, 1-2 producers

    const int* __restrict__ lb = yt + b * L_LEN;
    const float* __restrict__ yhb = yh + (size_t)b * T_LEN * C_DIM;

    if (wid >= 1) {
        // ---- two producers: each streams half of each chunk ---------------
        const int i0 = (wid == 1) ? 0 : TH;   // my row range within the chunk
        auto stage_half = [&](int ch) {       // TH rows x 2 dwordx4 = 32 loads
            float* d = &sbuf[ch & 1][0][0];
            const int row0 = dir == 0 ? ch * TC : T_LEN - TC * (ch + 1);
            const float* g = yhb + (size_t)row0 * C_DIM + lane * 4;
#pragma unroll
            for (int i = i0; i < i0 + TH; ++i) {
#pragma unroll
                for (int h = 0; h < 2; ++h) {
                    __builtin_amdgcn_global_load_lds(
                        (const __attribute__((address_space(1))) void*)
                            (g + i * C_DIM + h * 256),
                        (__attribute__((address_space(3))) void*)
                            (d + i * C_DIM + h * 256),
                        16, 0, 0);
                }
            }
        };
        stage_half(0);
        asm volatile("s_waitcnt vmcnt(0)" ::: "memory");
        __builtin_amdgcn_sched_barrier(0);
        __builtin_amdgcn_s_barrier();                      // raw: no auto-drain
#pragma unroll 1
        for (int c = 0; c < NCH; ++c) {
            if (c + 1 < NCH) stage_half(c + 1);            // lands under consumer chunk
            asm volatile("s_waitcnt vmcnt(0)" ::: "memory");
            __builtin_amdgcn_sched_barrier(0);
            __builtin_amdgcn_s_barrier();
        }
        return;
    }

    // -------- consumer -----------------------------------------------------
    const int l0 = lb[2 * lane];
    const int l1 = lb[2 * lane + 1];
    float* me = st + ((size_t)(dir * B_DIM + b) * 64 + lane) * 6;

    if (dir == 0) {
        // ================= forward: alpha_0 .. alpha_511 ===================
        const int lp = lane ? lb[2 * lane - 1] : 0;
        const float sk1 = (lane > 0 && l0 != lp && l0 != BLANK) ? 1.0f : 0.0f;
        const float sk3 = (l1 != l0 && l1 != BLANK) ? 1.0f : 0.0f;

        float a0 = (lane == 0) ? 1.0f : 0.0f;   // "t=-1" init trick
        float a1 = 0.0f, a2 = 0.0f, a3 = 0.0f, a4 = 0.0f;
        int   E  = 0;
        float sSeed = (lane == 0) ? 0.0f : 1.0f;

        __builtin_amdgcn_s_barrier();

        float r1[8], r3[8], rb[8];
#pragma unroll 1
        for (int c = 0; c < NCH; ++c) {
            __builtin_amdgcn_sched_barrier(0);
            const float* sb = &sbuf[c & 1][0][0];
#pragma unroll
            for (int i = 0; i < 8; ++i) {
                r1[i] = sb[i * C_DIM + l0];
                r3[i] = sb[i * C_DIM + l1];
                rb[i] = sb[i * C_DIM + BLANK];
            }
#pragma unroll
            for (int tq = 0; tq < TC / 8; ++tq) {
#pragma unroll
                for (int i = 0; i < 8; ++i) {
                    const float P1 = r1[i] + EPSF;
                    const float P3 = r3[i] + EPSF;
                    const float Pb = rb[i] + EPSF;
                    if (tq < TC / 8 - 1) {
                        const int tn = tq * 8 + i + 8;
                        r1[i] = sb[tn * C_DIM + l0];
                        r3[i] = sb[tn * C_DIM + l1];
                        rb[i] = sb[tn * C_DIM + BLANK];
                    }
                    const float pa3 = wshr1_f(a3) * sSeed;
                    const float n0 = Pb * (a0 + pa3);
                    const float n1 = P1 * (a1 + a0 + sk1 * pa3);
                    const float n2 = Pb * (a2 + a1);
                    const float n3 = P3 * (a3 + a2 + sk3 * a1);
                    const float n4 = Pb * (a4 + a3);
                    a0 = n0; a1 = n1; a2 = n2; a3 = n3; a4 = n4;

                    if ((i & 3) == 3) {
                        const float m = fmaxf(fmaxf(fmaxf(a0, a1), fmaxf(a2, a3)), a4);
                        const bool has = m > 0.0f;
                        int eb = (int)((__float_as_uint(m) >> 23) & 0xFFu);
                        eb = eb < 1 ? 1 : eb;
                        if (has) {
                            const float scl = __uint_as_float((unsigned)(254 - eb) << 23);
                            a0 *= scl; a1 *= scl; a2 *= scl; a3 *= scl; a4 *= scl;
                            E += eb - 127;
                        }
                        int pE = wshr1_i(E);
                        if (!has && lane > 0) E = pE;
                        pE = wshr1_i(E);
                        const int d = pE - E;
                        sSeed = (lane == 0 || d < -126)
                              ? 0.0f
                              : __uint_as_float((unsigned)(127 + (d > 126 ? 126 : d)) << 23);
                    }
                }
            }
            __builtin_amdgcn_sched_barrier(0);
            __builtin_amdgcn_s_barrier();
        }
        me[0] = a0; me[1] = a1; me[2] = a2; me[3] = a3; me[4] = a4;
        me[5] = __int_as_float(E);
    } else {
        // ================= backward: gamma_1023 -> gamma_511 ===============
        const float skb1 = (l1 != l0 && l1 != BLANK) ? 1.0f : 0.0f;   // 4l+1 -> 4l+3
        const int ln = (lane < 63) ? lb[2 * lane + 2] : 0;            // label(4l+5)
        const float skb3 = (lane < 63 && ln != l1 && ln != BLANK) ? 1.0f : 0.0f;

        float c0 = 0.0f, c1 = 0.0f, c2 = 0.0f;
        float c3 = (lane == 63) ? 1.0f : 0.0f;   // gamma_1023[255]=1
        float c4 = (lane == 63) ? 1.0f : 0.0f;   // gamma_1023[256]=1
        int   E  = 0;
        float sSeed = (lane == 63) ? 0.0f : 1.0f;

        __builtin_amdgcn_s_barrier();

        float r1[8], r3[8], rb[8];
#pragma unroll 1
        for (int c = 0; c < NCH; ++c) {
            __builtin_amdgcn_sched_barrier(0);
            const float* sb = &sbuf[c & 1][0][0];
            // step j consumes LDS row (TC-1-j): t descending within chunk
#pragma unroll
            for (int i = 0; i < 8; ++i) {
                const int rr = TC - 1 - i;
                r1[i] = sb[rr * C_DIM + l0];
                r3[i] = sb[rr * C_DIM + l1];
                rb[i] = sb[rr * C_DIM + BLANK];
            }
#pragma unroll
            for (int tq = 0; tq < TC / 8; ++tq) {
#pragma unroll
                for (int i = 0; i < 8; ++i) {
                    const float P1 = r1[i] + EPSF;
                    const float P3 = r3[i] + EPSF;
                    const float Pb = rb[i] + EPSF;
                    if (tq < TC / 8 - 1) {
                        const int rr = TC - 1 - (tq * 8 + i + 8);
                        r1[i] = sb[rr * C_DIM + l0];
                        r3[i] = sb[rr * C_DIM + l1];
                        rb[i] = sb[rr * C_DIM + BLANK];
                    }
                    const float bn0 = c0 * Pb;
                    const float bn1 = c1 * P1;
                    const float bn2 = c2 * Pb;
                    const float bn3 = c3 * P3;
                    const float bn4 = c4 * Pb;            // == neighbor's bn0
                    const float x1  = wshl1_f(bn1) * sSeed;
                    c0 = bn0 + bn1;
                    c1 = bn1 + bn2 + skb1 * bn3;
                    c2 = bn2 + bn3;
                    c3 = bn3 + bn4 + skb3 * x1;
                    c4 = bn4 + x1;

                    if ((i & 3) == 3) {
                        const float m = fmaxf(fmaxf(fmaxf(c0, c1), fmaxf(c2, c3)), c4);
                        const bool has = m > 0.0f;
                        int eb = (int)((__float_as_uint(m) >> 23) & 0xFFu);
                        eb = eb < 1 ? 1 : eb;
                        if (has) {
                            const float scl = __uint_as_float((unsigned)(254 - eb) << 23);
                            c0 *= scl; c1 *= scl; c2 *= scl; c3 *= scl; c4 *= scl;
                            E += eb - 127;
                        }
                        int pE = wshl1_i(E);
                        if (!has && lane < 63) E = pE;
                        pE = wshl1_i(E);
                        const int d = pE - E;
                        sSeed = (lane == 63 || d < -126)
                              ? 0.0f
                              : __uint_as_float((unsigned)(127 + (d > 126 ? 126 : d)) << 23);
                    }
                }
            }
            __builtin_amdgcn_sched_barrier(0);
            __builtin_amdgcn_s_barrier();
        }
        me[0] = c0; me[1] = c1; me[2] = c2; me[3] = c3; me[4] = c4;
        me[5] = __int_as_float(E);
    }
}

__global__ __launch_bounds__(64)
void ctc_combine(const float* __restrict__ st, float* __restrict__ out)
{
    const int b    = blockIdx.x;
    const int lane = threadIdx.x;
    const float* f = st + ((size_t)b * 64 + lane) * 6;
    const float* g = st + ((size_t)(B_DIM + b) * 64 + lane) * 6;

    float v = f[0] * g[0] + f[1] * g[1] + f[2] * g[2] + f[3] * g[3];
    if (lane == 63) v += f[4] * g[4];        // state 256
    const int e = __float_as_int(f[5]) + __float_as_int(g[5]);
    float L = (v > 0.0f) ? (log2f(v) + (float)e) : -1e30f;

    float M = L;
#pragma unroll
    for (int d = 1; d < 64; d <<= 1) M = fmaxf(M, __shfl_xor(M, d));
    float s = (L > -1e29f) ? exp2f(L - M) : 0.0f;
#pragma unroll
    for (int d = 1; d < 64; d <<= 1) s += __shfl_xor(s, d);

    if (lane == 0) out[b] = -((M + log2f(s)) * LN2F);
}

extern "C" void kernel_launch(void* const* d_in, const int* in_sizes, int n_in,
                              void* d_out, int out_size, void* d_ws, size_t ws_size,
                              hipStream_t stream)
{
    const int*   yt  = (const int*)d_in[0];
    const float* yh  = (const float*)d_in[1];
    float*       out = (float*)d_out;
    float*       st  = (float*)d_ws;       // 2*64*64*6 floats = 192 KB << ws
    ctc_fb<<<dim3(2 * B_DIM), dim3(192), 0, stream>>>(yt, yh, st);
    ctc_combine<<<dim3(B_DIM), dim3(64), 0, stream>>>(st, out);
}

// Round 22
// 40.597 us; speedup vs baseline: 1.0060x; 1.0060x over previous
//
#include <hip/hip_runtime.h>

// CTC batch cost (Keras: blank=C-1, full lengths).
// Structure (proven absmax 0.0 since R17): fwd/bwd split, 128 blocks;
//   block 2b+0 = forward alpha t=0..511, 2b+1 = backward beta t=1023..512;
//   P(y)=sum_s alpha*beta via ctc_combine. Consumer = R17 8-deep LDS ring +
//   DPP chain + per-lane pow2 rescale (unchanged, proven).
// R22 experiment: producer switches from global_load_lds to REG-STAGING
//   (plain global_load_dwordx4 -> VGPR, then ds_write_b128). Six variants
//   (R16-R21) pinned at ~30 GB/s/CU ingest on the global_load_lds path;
//   this tests whether the direct-to-LDS path itself is the limiter vs the
//   normal L1 VGPR-return path (64 B/cyc capable). Groups of 8 rows
//   (64 staging VGPRs) for load-batch overlap; compiler handles load->write
//   waits; explicit lgkmcnt(0) before the raw s_barrier for visibility.
// Fork: ~28-32us => path was the wall; ~40-42us => per-CU ingest ceiling
//   is path-independent -> structural roofline.

constexpr int   B_DIM = 64;
constexpr int   T_LEN = 1024;
constexpr int   C_DIM = 512;
constexpr int   L_LEN = 128;
constexpr int   BLANK = C_DIM - 1;
constexpr int   HALF  = T_LEN / 2;     // 512 steps per direction
constexpr int   TC    = 32;            // timesteps per chunk
constexpr int   NCH   = HALF / TC;     // 16 chunks
constexpr float EPSF  = 1e-7f;
constexpr float LN2F  = 0.69314718055994530942f;

// DPP lane shifts (bound_ctrl=0-fill). 0x138: lane l <- l-1 (verified R2-R21).
__device__ __forceinline__ float wshr1_f(float x) {
    return __int_as_float(__builtin_amdgcn_update_dpp(
        0, __float_as_int(x), 0x138, 0xf, 0xf, true));
}
__device__ __forceinline__ int wshr1_i(int x) {
    return __builtin_amdgcn_update_dpp(0, x, 0x138, 0xf, 0xf, true);
}
// 0x130: lane l <- l+1 (wave_shl:1), lane 63 gets 0. (verified R17)
__device__ __forceinline__ float wshl1_f(float x) {
    return __int_as_float(__builtin_amdgcn_update_dpp(
        0, __float_as_int(x), 0x130, 0xf, 0xf, true));
}
__device__ __forceinline__ int wshl1_i(int x) {
    return __builtin_amdgcn_update_dpp(0, x, 0x130, 0xf, 0xf, true);
}

__global__ __launch_bounds__(128, 1)
void ctc_fb(const int* __restrict__ yt, const float* __restrict__ yh,
            float* __restrict__ st)
{
    __shared__ float sbuf[2][TC][C_DIM];      // 128 KB

    const int bid  = blockIdx.x;
    const int b    = bid >> 1;
    const int dir  = bid & 1;                 // 0 = forward, 1 = backward
    const int tid  = threadIdx.x;
    const int lane = tid & 63;
    const int wid  = tid >> 6;                // 0 consumer, 1 producer

    const int* __restrict__ lb = yt + b * L_LEN;
    const float* __restrict__ yhb = yh + (size_t)b * T_LEN * C_DIM;

    if (wid == 1) {
        // ---- producer: REG-STAGED streaming (plain loads + ds_write) ------
        // Row = 512 floats = 128 float4; lane covers float4 slots lane, lane+64.
        auto stage = [&](int ch) {
            float* d = &sbuf[ch & 1][0][0];
            const int row0 = dir == 0 ? ch * TC : T_LEN - TC * (ch + 1);
            const float4* g = (const float4*)(yhb + (size_t)row0 * C_DIM) + lane;
#pragma unroll
            for (int i0 = 0; i0 < TC; i0 += 8) {
                float4 v0a, v0b, v1a, v1b, v2a, v2b, v3a, v3b;
                float4 v4a, v4b, v5a, v5b, v6a, v6b, v7a, v7b;
                v0a = g[(i0+0)*128]; v0b = g[(i0+0)*128 + 64];
                v1a = g[(i0+1)*128]; v1b = g[(i0+1)*128 + 64];
                v2a = g[(i0+2)*128]; v2b = g[(i0+2)*128 + 64];
                v3a = g[(i0+3)*128]; v3b = g[(i0+3)*128 + 64];
                v4a = g[(i0+4)*128]; v4b = g[(i0+4)*128 + 64];
                v5a = g[(i0+5)*128]; v5b = g[(i0+5)*128 + 64];
                v6a = g[(i0+6)*128]; v6b = g[(i0+6)*128 + 64];
                v7a = g[(i0+7)*128]; v7b = g[(i0+7)*128 + 64];
                float4* dd;
                dd = (float4*)(d + (i0+0)*C_DIM) + lane; dd[0] = v0a; dd[64] = v0b;
                dd = (float4*)(d + (i0+1)*C_DIM) + lane; dd[0] = v1a; dd[64] = v1b;
                dd = (float4*)(d + (i0+2)*C_DIM) + lane; dd[0] = v2a; dd[64] = v2b;
                dd = (float4*)(d + (i0+3)*C_DIM) + lane; dd[0] = v3a; dd[64] = v3b;
                dd = (float4*)(d + (i0+4)*C_DIM) + lane; dd[0] = v4a; dd[64] = v4b;
                dd = (float4*)(d + (i0+5)*C_DIM) + lane; dd[0] = v5a; dd[64] = v5b;
                dd = (float4*)(d + (i0+6)*C_DIM) + lane; dd[0] = v6a; dd[64] = v6b;
                dd = (float4*)(d + (i0+7)*C_DIM) + lane; dd[0] = v7a; dd[64] = v7b;
            }
        };
        stage(0);
        asm volatile("s_waitcnt vmcnt(0) lgkmcnt(0)" ::: "memory");
        __builtin_amdgcn_sched_barrier(0);
        __builtin_amdgcn_s_barrier();                      // raw: no auto-drain
#pragma unroll 1
        for (int c = 0; c < NCH; ++c) {
            if (c + 1 < NCH) stage(c + 1);                 // overlaps consumer chunk c
            asm volatile("s_waitcnt vmcnt(0) lgkmcnt(0)" ::: "memory");
            __builtin_amdgcn_sched_barrier(0);
            __builtin_amdgcn_s_barrier();
        }
        return;
    }

    // -------- consumer (unchanged, proven) ---------------------------------
    const int l0 = lb[2 * lane];
    const int l1 = lb[2 * lane + 1];
    float* me = st + ((size_t)(dir * B_DIM + b) * 64 + lane) * 6;

    if (dir == 0) {
        // ================= forward: alpha_0 .. alpha_511 ===================
        const int lp = lane ? lb[2 * lane - 1] : 0;
        const float sk1 = (lane > 0 && l0 != lp && l0 != BLANK) ? 1.0f : 0.0f;
        const float sk3 = (l1 != l0 && l1 != BLANK) ? 1.0f : 0.0f;

        float a0 = (lane == 0) ? 1.0f : 0.0f;   // "t=-1" init trick
        float a1 = 0.0f, a2 = 0.0f, a3 = 0.0f, a4 = 0.0f;
        int   E  = 0;
        float sSeed = (lane == 0) ? 0.0f : 1.0f;

        __builtin_amdgcn_s_barrier();

        float r1[8], r3[8], rb[8];
#pragma unroll 1
        for (int c = 0; c < NCH; ++c) {
            __builtin_amdgcn_sched_barrier(0);
            const float* sb = &sbuf[c & 1][0][0];
#pragma unroll
            for (int i = 0; i < 8; ++i) {
                r1[i] = sb[i * C_DIM + l0];
                r3[i] = sb[i * C_DIM + l1];
                rb[i] = sb[i * C_DIM + BLANK];
            }
#pragma unroll
            for (int tq = 0; tq < TC / 8; ++tq) {
#pragma unroll
                for (int i = 0; i < 8; ++i) {
                    const float P1 = r1[i] + EPSF;
                    const float P3 = r3[i] + EPSF;
                    const float Pb = rb[i] + EPSF;
                    if (tq < TC / 8 - 1) {
                        const int tn = tq * 8 + i + 8;
                        r1[i] = sb[tn * C_DIM + l0];
                        r3[i] = sb[tn * C_DIM + l1];
                        rb[i] = sb[tn * C_DIM + BLANK];
                    }
                    const float pa3 = wshr1_f(a3) * sSeed;
                    const float n0 = Pb * (a0 + pa3);
                    const float n1 = P1 * (a1 + a0 + sk1 * pa3);
                    const float n2 = Pb * (a2 + a1);
                    const float n3 = P3 * (a3 + a2 + sk3 * a1);
                    const float n4 = Pb * (a4 + a3);
                    a0 = n0; a1 = n1; a2 = n2; a3 = n3; a4 = n4;

                    if ((i & 3) == 3) {
                        const float m = fmaxf(fmaxf(fmaxf(a0, a1), fmaxf(a2, a3)), a4);
                        const bool has = m > 0.0f;
                        int eb = (int)((__float_as_uint(m) >> 23) & 0xFFu);
                        eb = eb < 1 ? 1 : eb;
                        if (has) {
                            const float scl = __uint_as_float((unsigned)(254 - eb) << 23);
                            a0 *= scl; a1 *= scl; a2 *= scl; a3 *= scl; a4 *= scl;
                            E += eb - 127;
                        }
                        int pE = wshr1_i(E);
                        if (!has && lane > 0) E = pE;
                        pE = wshr1_i(E);
                        const int d = pE - E;
                        sSeed = (lane == 0 || d < -126)
                              ? 0.0f
                              : __uint_as_float((unsigned)(127 + (d > 126 ? 126 : d)) << 23);
                    }
                }
            }
            __builtin_amdgcn_sched_barrier(0);
            __builtin_amdgcn_s_barrier();
        }
        me[0] = a0; me[1] = a1; me[2] = a2; me[3] = a3; me[4] = a4;
        me[5] = __int_as_float(E);
    } else {
        // ================= backward: gamma_1023 -> gamma_511 ===============
        const float skb1 = (l1 != l0 && l1 != BLANK) ? 1.0f : 0.0f;   // 4l+1 -> 4l+3
        const int ln = (lane < 63) ? lb[2 * lane + 2] : 0;            // label(4l+5)
        const float skb3 = (lane < 63 && ln != l1 && ln != BLANK) ? 1.0f : 0.0f;

        float c0 = 0.0f, c1 = 0.0f, c2 = 0.0f;
        float c3 = (lane == 63) ? 1.0f : 0.0f;   // gamma_1023[255]=1
        float c4 = (lane == 63) ? 1.0f : 0.0f;   // gamma_1023[256]=1
        int   E  = 0;
        float sSeed = (lane == 63) ? 0.0f : 1.0f;

        __builtin_amdgcn_s_barrier();

        float r1[8], r3[8], rb[8];
#pragma unroll 1
        for (int c = 0; c < NCH; ++c) {
            __builtin_amdgcn_sched_barrier(0);
            const float* sb = &sbuf[c & 1][0][0];
            // step j consumes LDS row (TC-1-j): t descending within chunk
#pragma unroll
            for (int i = 0; i < 8; ++i) {
                const int rr = TC - 1 - i;
                r1[i] = sb[rr * C_DIM + l0];
                r3[i] = sb[rr * C_DIM + l1];
                rb[i] = sb[rr * C_DIM + BLANK];
            }
#pragma unroll
            for (int tq = 0; tq < TC / 8; ++tq) {
#pragma unroll
                for (int i = 0; i < 8; ++i) {
                    const float P1 = r1[i] + EPSF;
                    const float P3 = r3[i] + EPSF;
                    const float Pb = rb[i] + EPSF;
                    if (tq < TC / 8 - 1) {
                        const int rr = TC - 1 - (tq * 8 + i + 8);
                        r1[i] = sb[rr * C_DIM + l0];
                        r3[i] = sb[rr * C_DIM + l1];
                        rb[i] = sb[rr * C_DIM + BLANK];
                    }
                    const float bn0 = c0 * Pb;
                    const float bn1 = c1 * P1;
                    const float bn2 = c2 * Pb;
                    const float bn3 = c3 * P3;
                    const float bn4 = c4 * Pb;            // == neighbor's bn0
                    const float x1  = wshl1_f(bn1) * sSeed;
                    c0 = bn0 + bn1;
                    c1 = bn1 + bn2 + skb1 * bn3;
                    c2 = bn2 + bn3;
                    c3 = bn3 + bn4 + skb3 * x1;
                    c4 = bn4 + x1;

                    if ((i & 3) == 3) {
                        const float m = fmaxf(fmaxf(fmaxf(c0, c1), fmaxf(c2, c3)), c4);
                        const bool has = m > 0.0f;
                        int eb = (int)((__float_as_uint(m) >> 23) & 0xFFu);
                        eb = eb < 1 ? 1 : eb;
                        if (has) {
                            const float scl = __uint_as_float((unsigned)(254 - eb) << 23);
                            c0 *= scl; c1 *= scl; c2 *= scl; c3 *= scl; c4 *= scl;
                            E += eb - 127;
                        }
                        int pE = wshl1_i(E);
                        if (!has && lane < 63) E = pE;
                        pE = wshl1_i(E);
                        const int d = pE - E;
                        sSeed = (lane == 63 || d < -126)
                              ? 0.0f
                              : __uint_as_float((unsigned)(127 + (d > 126 ? 126 : d)) << 23);
                    }
                }
            }
            __builtin_amdgcn_sched_barrier(0);
            __builtin_amdgcn_s_barrier();
        }
        me[0] = c0; me[1] = c1; me[2] = c2; me[3] = c3; me[4] = c4;
        me[5] = __int_as_float(E);
    }
}

__global__ __launch_bounds__(64)
void ctc_combine(const float* __restrict__ st, float* __restrict__ out)
{
    const int b    = blockIdx.x;
    const int lane = threadIdx.x;
    const float* f = st + ((size_t)b * 64 + lane) * 6;
    const float* g = st + ((size_t)(B_DIM + b) * 64 + lane) * 6;

    float v = f[0] * g[0] + f[1] * g[1] + f[2] * g[2] + f[3] * g[3];
    if (lane == 63) v += f[4] * g[4];        // state 256
    const int e = __float_as_int(f[5]) + __float_as_int(g[5]);
    float L = (v > 0.0f) ? (log2f(v) + (float)e) : -1e30f;

    float M = L;
#pragma unroll
    for (int d = 1; d < 64; d <<= 1) M = fmaxf(M, __shfl_xor(M, d));
    float s = (L > -1e29f) ? exp2f(L - M) : 0.0f;
#pragma unroll
    for (int d = 1; d < 64; d <<= 1) s += __shfl_xor(s, d);

    if (lane == 0) out[b] = -((M + log2f(s)) * LN2F);
}

extern "C" void kernel_launch(void* const* d_in, const int* in_sizes, int n_in,
                              void* d_out, int out_size, void* d_ws, size_t ws_size,
                              hipStream_t stream)
{
    const int*   yt  = (const int*)d_in[0];
    const float* yh  = (const float*)d_in[1];
    float*       out = (float*)d_out;
    float*       st  = (float*)d_ws;       // 2*64*64*6 floats = 192 KB << ws
    ctc_fb<<<dim3(2 * B_DIM), dim3(128), 0, stream>>>(yt, yh, st);
    ctc_combine<<<dim3(B_DIM), dim3(64), 0, stream>>>(st, out);
}

// Round 23
// 37.968 us; speedup vs baseline: 1.0756x; 1.0692x over previous
//
#include <hip/hip_runtime.h>

// CTC batch cost (Keras: blank=C-1, full lengths).
// Structure (proven absmax 0.0 since R17): fwd/bwd split, 128 blocks;
//   block 2b+0 = forward alpha t=0..511, 2b+1 = backward beta t=1023..512;
//   P(y)=sum_s alpha*beta via ctc_combine.
// R23 (consumer-side, after 8 producer-side nulls R16-R22):
//   1. EPS folded into the reg-staging producer (touches every value in
//      VGPRs anyway; consumer loses 3 v_add/step).
//   2. Per-lane pow2 rescale every 8 steps (was 4): halves both the rescale
//      issue cost and the exposed ~60-70cyc serial chain (fmax tree ->
//      exp-extract -> apply -> 2x DPP on E -> sSeed build) that the next
//      step's DP depends on. Per-LANE exponents keep dynamic range; only
//      intra-lane spread >2^38 within an 8-step window flushes (negligible).

constexpr int   B_DIM = 64;
constexpr int   T_LEN = 1024;
constexpr int   C_DIM = 512;
constexpr int   L_LEN = 128;
constexpr int   BLANK = C_DIM - 1;
constexpr int   HALF  = T_LEN / 2;     // 512 steps per direction
constexpr int   TC    = 32;            // timesteps per chunk
constexpr int   NCH   = HALF / TC;     // 16 chunks
constexpr float EPSF  = 1e-7f;
constexpr float LN2F  = 0.69314718055994530942f;

// DPP lane shifts (bound_ctrl=0-fill). 0x138: lane l <- l-1 (verified R2-R22).
__device__ __forceinline__ float wshr1_f(float x) {
    return __int_as_float(__builtin_amdgcn_update_dpp(
        0, __float_as_int(x), 0x138, 0xf, 0xf, true));
}
__device__ __forceinline__ int wshr1_i(int x) {
    return __builtin_amdgcn_update_dpp(0, x, 0x138, 0xf, 0xf, true);
}
// 0x130: lane l <- l+1 (wave_shl:1), lane 63 gets 0. (verified R17)
__device__ __forceinline__ float wshl1_f(float x) {
    return __int_as_float(__builtin_amdgcn_update_dpp(
        0, __float_as_int(x), 0x130, 0xf, 0xf, true));
}
__device__ __forceinline__ int wshl1_i(int x) {
    return __builtin_amdgcn_update_dpp(0, x, 0x130, 0xf, 0xf, true);
}

__device__ __forceinline__ float4 addeps(float4 v) {
    v.x += EPSF; v.y += EPSF; v.z += EPSF; v.w += EPSF; return v;
}

__global__ __launch_bounds__(128, 1)
void ctc_fb(const int* __restrict__ yt, const float* __restrict__ yh,
            float* __restrict__ st)
{
    __shared__ float sbuf[2][TC][C_DIM];      // 128 KB

    const int bid  = blockIdx.x;
    const int b    = bid >> 1;
    const int dir  = bid & 1;                 // 0 = forward, 1 = backward
    const int tid  = threadIdx.x;
    const int lane = tid & 63;
    const int wid  = tid >> 6;                // 0 consumer, 1 producer

    const int* __restrict__ lb = yt + b * L_LEN;
    const float* __restrict__ yhb = yh + (size_t)b * T_LEN * C_DIM;

    if (wid == 1) {
        // ---- producer: reg-staged streaming, EPS folded during staging ----
        auto stage = [&](int ch) {
            float* d = &sbuf[ch & 1][0][0];
            const int row0 = dir == 0 ? ch * TC : T_LEN - TC * (ch + 1);
            const float4* g = (const float4*)(yhb + (size_t)row0 * C_DIM) + lane;
#pragma unroll
            for (int i0 = 0; i0 < TC; i0 += 8) {
                float4 v0a, v0b, v1a, v1b, v2a, v2b, v3a, v3b;
                float4 v4a, v4b, v5a, v5b, v6a, v6b, v7a, v7b;
                v0a = g[(i0+0)*128]; v0b = g[(i0+0)*128 + 64];
                v1a = g[(i0+1)*128]; v1b = g[(i0+1)*128 + 64];
                v2a = g[(i0+2)*128]; v2b = g[(i0+2)*128 + 64];
                v3a = g[(i0+3)*128]; v3b = g[(i0+3)*128 + 64];
                v4a = g[(i0+4)*128]; v4b = g[(i0+4)*128 + 64];
                v5a = g[(i0+5)*128]; v5b = g[(i0+5)*128 + 64];
                v6a = g[(i0+6)*128]; v6b = g[(i0+6)*128 + 64];
                v7a = g[(i0+7)*128]; v7b = g[(i0+7)*128 + 64];
                v0a = addeps(v0a); v0b = addeps(v0b);
                v1a = addeps(v1a); v1b = addeps(v1b);
                v2a = addeps(v2a); v2b = addeps(v2b);
                v3a = addeps(v3a); v3b = addeps(v3b);
                v4a = addeps(v4a); v4b = addeps(v4b);
                v5a = addeps(v5a); v5b = addeps(v5b);
                v6a = addeps(v6a); v6b = addeps(v6b);
                v7a = addeps(v7a); v7b = addeps(v7b);
                float4* dd;
                dd = (float4*)(d + (i0+0)*C_DIM) + lane; dd[0] = v0a; dd[64] = v0b;
                dd = (float4*)(d + (i0+1)*C_DIM) + lane; dd[0] = v1a; dd[64] = v1b;
                dd = (float4*)(d + (i0+2)*C_DIM) + lane; dd[0] = v2a; dd[64] = v2b;
                dd = (float4*)(d + (i0+3)*C_DIM) + lane; dd[0] = v3a; dd[64] = v3b;
                dd = (float4*)(d + (i0+4)*C_DIM) + lane; dd[0] = v4a; dd[64] = v4b;
                dd = (float4*)(d + (i0+5)*C_DIM) + lane; dd[0] = v5a; dd[64] = v5b;
                dd = (float4*)(d + (i0+6)*C_DIM) + lane; dd[0] = v6a; dd[64] = v6b;
                dd = (float4*)(d + (i0+7)*C_DIM) + lane; dd[0] = v7a; dd[64] = v7b;
            }
        };
        stage(0);
        asm volatile("s_waitcnt vmcnt(0) lgkmcnt(0)" ::: "memory");
        __builtin_amdgcn_sched_barrier(0);
        __builtin_amdgcn_s_barrier();                      // raw: no auto-drain
#pragma unroll 1
        for (int c = 0; c < NCH; ++c) {
            if (c + 1 < NCH) stage(c + 1);                 // overlaps consumer chunk c
            asm volatile("s_waitcnt vmcnt(0) lgkmcnt(0)" ::: "memory");
            __builtin_amdgcn_sched_barrier(0);
            __builtin_amdgcn_s_barrier();
        }
        return;
    }

    // -------- consumer (EPS pre-folded; rescale every 8) -------------------
    const int l0 = lb[2 * lane];
    const int l1 = lb[2 * lane + 1];
    float* me = st + ((size_t)(dir * B_DIM + b) * 64 + lane) * 6;

    if (dir == 0) {
        // ================= forward: alpha_0 .. alpha_511 ===================
        const int lp = lane ? lb[2 * lane - 1] : 0;
        const float sk1 = (lane > 0 && l0 != lp && l0 != BLANK) ? 1.0f : 0.0f;
        const float sk3 = (l1 != l0 && l1 != BLANK) ? 1.0f : 0.0f;

        float a0 = (lane == 0) ? 1.0f : 0.0f;   // "t=-1" init trick
        float a1 = 0.0f, a2 = 0.0f, a3 = 0.0f, a4 = 0.0f;
        int   E  = 0;
        float sSeed = (lane == 0) ? 0.0f : 1.0f;

        __builtin_amdgcn_s_barrier();

        float r1[8], r3[8], rb[8];
#pragma unroll 1
        for (int c = 0; c < NCH; ++c) {
            __builtin_amdgcn_sched_barrier(0);
            const float* sb = &sbuf[c & 1][0][0];
#pragma unroll
            for (int i = 0; i < 8; ++i) {
                r1[i] = sb[i * C_DIM + l0];
                r3[i] = sb[i * C_DIM + l1];
                rb[i] = sb[i * C_DIM + BLANK];
            }
#pragma unroll
            for (int tq = 0; tq < TC / 8; ++tq) {
#pragma unroll
                for (int i = 0; i < 8; ++i) {
                    const float P1 = r1[i];
                    const float P3 = r3[i];
                    const float Pb = rb[i];
                    if (tq < TC / 8 - 1) {
                        const int tn = tq * 8 + i + 8;
                        r1[i] = sb[tn * C_DIM + l0];
                        r3[i] = sb[tn * C_DIM + l1];
                        rb[i] = sb[tn * C_DIM + BLANK];
                    }
                    const float pa3 = wshr1_f(a3) * sSeed;
                    const float n0 = Pb * (a0 + pa3);
                    const float n1 = P1 * (a1 + a0 + sk1 * pa3);
                    const float n2 = Pb * (a2 + a1);
                    const float n3 = P3 * (a3 + a2 + sk3 * a1);
                    const float n4 = Pb * (a4 + a3);
                    a0 = n0; a1 = n1; a2 = n2; a3 = n3; a4 = n4;

                    if (i == 7) {
                        // per-lane rescale every 8 steps
                        const float m = fmaxf(fmaxf(fmaxf(a0, a1), fmaxf(a2, a3)), a4);
                        const bool has = m > 0.0f;
                        int eb = (int)((__float_as_uint(m) >> 23) & 0xFFu);
                        eb = eb < 1 ? 1 : eb;
                        if (has) {
                            const float scl = __uint_as_float((unsigned)(254 - eb) << 23);
                            a0 *= scl; a1 *= scl; a2 *= scl; a3 *= scl; a4 *= scl;
                            E += eb - 127;
                        }
                        int pE = wshr1_i(E);
                        if (!has && lane > 0) E = pE;
                        pE = wshr1_i(E);
                        const int d = pE - E;
                        sSeed = (lane == 0 || d < -126)
                              ? 0.0f
                              : __uint_as_float((unsigned)(127 + (d > 126 ? 126 : d)) << 23);
                    }
                }
            }
            __builtin_amdgcn_sched_barrier(0);
            __builtin_amdgcn_s_barrier();
        }
        me[0] = a0; me[1] = a1; me[2] = a2; me[3] = a3; me[4] = a4;
        me[5] = __int_as_float(E);
    } else {
        // ================= backward: gamma_1023 -> gamma_511 ===============
        const float skb1 = (l1 != l0 && l1 != BLANK) ? 1.0f : 0.0f;   // 4l+1 -> 4l+3
        const int ln = (lane < 63) ? lb[2 * lane + 2] : 0;            // label(4l+5)
        const float skb3 = (lane < 63 && ln != l1 && ln != BLANK) ? 1.0f : 0.0f;

        float c0 = 0.0f, c1 = 0.0f, c2 = 0.0f;
        float c3 = (lane == 63) ? 1.0f : 0.0f;   // gamma_1023[255]=1
        float c4 = (lane == 63) ? 1.0f : 0.0f;   // gamma_1023[256]=1
        int   E  = 0;
        float sSeed = (lane == 63) ? 0.0f : 1.0f;

        __builtin_amdgcn_s_barrier();

        float r1[8], r3[8], rb[8];
#pragma unroll 1
        for (int c = 0; c < NCH; ++c) {
            __builtin_amdgcn_sched_barrier(0);
            const float* sb = &sbuf[c & 1][0][0];
            // step j consumes LDS row (TC-1-j): t descending within chunk
#pragma unroll
            for (int i = 0; i < 8; ++i) {
                const int rr = TC - 1 - i;
                r1[i] = sb[rr * C_DIM + l0];
                r3[i] = sb[rr * C_DIM + l1];
                rb[i] = sb[rr * C_DIM + BLANK];
            }
#pragma unroll
            for (int tq = 0; tq < TC / 8; ++tq) {
#pragma unroll
                for (int i = 0; i < 8; ++i) {
                    const float P1 = r1[i];
                    const float P3 = r3[i];
                    const float Pb = rb[i];
                    if (tq < TC / 8 - 1) {
                        const int rr = TC - 1 - (tq * 8 + i + 8);
                        r1[i] = sb[rr * C_DIM + l0];
                        r3[i] = sb[rr * C_DIM + l1];
                        rb[i] = sb[rr * C_DIM + BLANK];
                    }
                    const float bn0 = c0 * Pb;
                    const float bn1 = c1 * P1;
                    const float bn2 = c2 * Pb;
                    const float bn3 = c3 * P3;
                    const float bn4 = c4 * Pb;            // == neighbor's bn0
                    const float x1  = wshl1_f(bn1) * sSeed;
                    c0 = bn0 + bn1;
                    c1 = bn1 + bn2 + skb1 * bn3;
                    c2 = bn2 + bn3;
                    c3 = bn3 + bn4 + skb3 * x1;
                    c4 = bn4 + x1;

                    if (i == 7) {
                        // per-lane rescale every 8 steps
                        const float m = fmaxf(fmaxf(fmaxf(c0, c1), fmaxf(c2, c3)), c4);
                        const bool has = m > 0.0f;
                        int eb = (int)((__float_as_uint(m) >> 23) & 0xFFu);
                        eb = eb < 1 ? 1 : eb;
                        if (has) {
                            const float scl = __uint_as_float((unsigned)(254 - eb) << 23);
                            c0 *= scl; c1 *= scl; c2 *= scl; c3 *= scl; c4 *= scl;
                            E += eb - 127;
                        }
                        int pE = wshl1_i(E);
                        if (!has && lane < 63) E = pE;
                        pE = wshl1_i(E);
                        const int d = pE - E;
                        sSeed = (lane == 63 || d < -126)
                              ? 0.0f
                              : __uint_as_float((unsigned)(127 + (d > 126 ? 126 : d)) << 23);
                    }
                }
            }
            __builtin_amdgcn_sched_barrier(0);
            __builtin_amdgcn_s_barrier();
        }
        me[0] = c0; me[1] = c1; me[2] = c2; me[3] = c3; me[4] = c4;
        me[5] = __int_as_float(E);
    }
}

__global__ __launch_bounds__(64)
void ctc_combine(const float* __restrict__ st, float* __restrict__ out)
{
    const int b    = blockIdx.x;
    const int lane = threadIdx.x;
    const float* f = st + ((size_t)b * 64 + lane) * 6;
    const float* g = st + ((size_t)(B_DIM + b) * 64 + lane) * 6;

    float v = f[0] * g[0] + f[1] * g[1] + f[2] * g[2] + f[3] * g[3];
    if (lane == 63) v += f[4] * g[4];        // state 256
    const int e = __float_as_int(f[5]) + __float_as_int(g[5]);
    float L = (v > 0.0f) ? (log2f(v) + (float)e) : -1e30f;

    float M = L;
#pragma unroll
    for (int d = 1; d < 64; d <<= 1) M = fmaxf(M, __shfl_xor(M, d));
    float s = (L > -1e29f) ? exp2f(L - M) : 0.0f;
#pragma unroll
    for (int d = 1; d < 64; d <<= 1) s += __shfl_xor(s, d);

    if (lane == 0) out[b] = -((M + log2f(s)) * LN2F);
}

extern "C" void kernel_launch(void* const* d_in, const int* in_sizes, int n_in,
                              void* d_out, int out_size, void* d_ws, size_t ws_size,
                              hipStream_t stream)
{
    const int*   yt  = (const int*)d_in[0];
    const float* yh  = (const float*)d_in[1];
    float*       out = (float*)d_out;
    float*       st  = (float*)d_ws;       // 2*64*64*6 floats = 192 KB << ws
    ctc_fb<<<dim3(2 * B_DIM), dim3(128), 0, stream>>>(yt, yh, st);
    ctc_combine<<<dim3(B_DIM), dim3(64), 0, stream>>>(st, out);
}